// Round 2
// baseline (64.081 us; speedup 1.0000x reference)
//
#include <hip/hip_runtime.h>

// out[b, r, c] = x[b, r, c] - (r >= 2 ? x[b, r-2, c] : 0)
// x: (32, 1, 1024, 1024) float32. W = 1024 floats = 256 float4 per row.
// Image = 1024 rows; row-in-image for float4 index i is (i >> 8) & 1023.
// 2-row shift = 512 float4s.

__global__ __launch_bounds__(256) void dir2_diff_kernel(
    const float4* __restrict__ x, float4* __restrict__ out, int n4) {
  int i = blockIdx.x * blockDim.x + threadIdx.x;
  const int stride = gridDim.x * blockDim.x;
  for (; i < n4; i += stride) {
    float4 a = x[i];
    int row = (i >> 8) & 1023;  // row within the 1024x1024 image
    float4 s = make_float4(0.f, 0.f, 0.f, 0.f);
    if (row >= 2) s = x[i - 512];
    out[i] = make_float4(a.x - s.x, a.y - s.y, a.z - s.z, a.w - s.w);
  }
}

extern "C" void kernel_launch(void* const* d_in, const int* in_sizes, int n_in,
                              void* d_out, int out_size, void* d_ws, size_t ws_size,
                              hipStream_t stream) {
  const float4* x = (const float4*)d_in[0];
  float4* out = (float4*)d_out;
  const int n4 = in_sizes[0] / 4;  // 32*1024*1024 / 4 = 8388608

  const int block = 256;
  int grid = (n4 + block - 1) / block;
  if (grid > 2048) grid = 2048;  // 8 blocks/CU on 256 CUs, grid-stride the rest
  dir2_diff_kernel<<<grid, block, 0, stream>>>(x, out, n4);
}

// Round 3
// 45.837 us; speedup vs baseline: 1.3980x; 1.3980x over previous
//
#include <hip/hip_runtime.h>

// out[b, r, c] = x[b, r, c] - (r >= 2 ? x[b, r-2, c] : 0)
// x: (32, 1, 1024, 1024) float32.
//
// Register-history version: each block owns a 32-row strip of one image.
// 256 threads = 256 float4 columns (1024 floats) of a row. The block walks
// the strip top->bottom; each thread keeps x[r-2], x[r-1] in registers so
// the shifted operand never issues a second global read (which previously
// missed the per-XCD L2 and doubled HBM fetch traffic).

__global__ __launch_bounds__(256) void dir2_diff_kernel(
    const float4* __restrict__ x, float4* __restrict__ out) {
  constexpr int W4 = 256;    // float4s per row
  constexpr int ROWS = 32;   // rows per block strip

  const int img = blockIdx.x >> 5;    // 32 chunks per image
  const int chunk = blockIdx.x & 31;
  const int r0 = chunk * ROWS;
  const int c = threadIdx.x;

  const float4* __restrict__ xb = x + ((size_t)img << 18);  // 1024*256 float4/image
  float4* __restrict__ ob = out + ((size_t)img << 18);

  const float4 zero = make_float4(0.f, 0.f, 0.f, 0.f);
  // History prologue: rows r0-2, r0-1 (zero if out of image).
  float4 s_m2 = (r0 >= 2) ? xb[(r0 - 2) * W4 + c] : zero;
  float4 s_m1 = (r0 >= 1) ? xb[(r0 - 1) * W4 + c] : zero;

  int idx = r0 * W4 + c;
#pragma unroll 8
  for (int r = 0; r < ROWS; ++r, idx += W4) {
    float4 a = xb[idx];
    float4 o;
    o.x = a.x - s_m2.x;
    o.y = a.y - s_m2.y;
    o.z = a.z - s_m2.z;
    o.w = a.w - s_m2.w;
    ob[idx] = o;
    s_m2 = s_m1;
    s_m1 = a;
  }
}

extern "C" void kernel_launch(void* const* d_in, const int* in_sizes, int n_in,
                              void* d_out, int out_size, void* d_ws, size_t ws_size,
                              hipStream_t stream) {
  const float4* x = (const float4*)d_in[0];
  float4* out = (float4*)d_out;
  // 32 images * (1024 rows / 32 rows-per-block) = 1024 blocks
  dir2_diff_kernel<<<1024, 256, 0, stream>>>(x, out);
}